// Round 1
// baseline (176.715 us; speedup 1.0000x reference)
//
#include <hip/hip_runtime.h>

// Series decomposition: T = moving_avg_C(x, k=25, replicate pad), xd = x - T,
// S = per-phase (c % 24) mean over G=14 groups of xd, R = xd - S.
// x: [B=32, C=336, HW=1024] fp32; outputs T,S,R.
//
// R4: store-drain removal. R3 issued T-stores inside the window pass and then
// hit __syncthreads(), whose barrier semantics force s_waitcnt vmcnt(0) --
// draining 10,752 NT stores per block mid-kernel with all 14 waves parked.
// Here ALL global stores (T,S,R) are deferred to a single epilogue after the
// final barrier: barriers 2-4 have no outstanding vmem ops (their vmcnt(0)
// is free) and the epilogue stores retire asynchronously, overlapped with the
// next resident block. Staging now uses global_load_lds dwordx4 (compiler
// never auto-emits it), freeing the 3x float4 staging registers so tval[12]
// fits in the 64-VGPR bucket (launch_bounds(896,8) -> 28 waves/CU, LDS
// 2x45 KiB resident).

#define C_TOT 336
#define HWSZ 1024
#define PERIOD 24
#define GROUPS 14         // C_TOT / PERIOD
#define PAD 12            // (25-1)/2
#define W 32              // hw tile width (floats) -> 128 B rows
#define SEG_C 12          // channels per thread
#define NSEG 28           // C_TOT / SEG_C
#define NTHREADS (NSEG * W)   // 896 = 14 waves

__device__ __forceinline__ void gload_lds16(const float4* g, float4* l) {
    // LDS dest is wave-uniform base + lane*16; our idx is lane-contiguous
    // per wave (idx = 64*w + ... + lane), so linear layout is preserved.
    __builtin_amdgcn_global_load_lds(
        (const __attribute__((address_space(1))) unsigned int*)g,
        (__attribute__((address_space(3))) unsigned int*)l,
        16, 0, 0);
}

__global__ __launch_bounds__(NTHREADS, 8) void decomp_kernel(
    const float* __restrict__ x,
    float* __restrict__ outT,
    float* __restrict__ outS,
    float* __restrict__ outR)
{
    __shared__ float sx[C_TOT][W];     // 43008 B; bank = col -> 2-way max (free)
    __shared__ float sv[PERIOD][W];    // 3072 B

    const int tid = threadIdx.x;
    const int b   = blockIdx.y;
    const int hw0 = blockIdx.x * W;

    // ---- Stage x[b, :, hw0:hw0+32] -> LDS via global_load_lds (16 B) ----
    const float4* __restrict__ xg =
        (const float4*)(x + (size_t)b * C_TOT * HWSZ + hw0);
    float4* sx4 = (float4*)sx;
    #pragma unroll
    for (int k = 0; k < 3; ++k) {
        const int idx = tid + k * NTHREADS;                  // 0..2687
        gload_lds16(xg + (idx >> 3) * (HWSZ / 4) + (idx & 7), sx4 + idx);
    }
    asm volatile("s_waitcnt vmcnt(0)" ::: "memory");
    __syncthreads();                    // barrier 1: staging visible

    const int col = tid & (W - 1);
    const int seg = tid >> 5;          // 0..27
    const int c0  = seg * SEG_C;       // 0..324
    const float inv25 = 1.0f / 25.0f;
    const float inv14 = 1.0f / (float)GROUPS;

    // ---- Window prologue: sum of x[c0-12 .. c0+12], two independent chains ----
    float wa = 0.0f, wb = 0.0f;
    #pragma unroll
    for (int d = -PAD; d <= PAD; d += 2) {
        int cc = c0 + d;
        cc = cc < 0 ? 0 : cc; cc = cc > C_TOT - 1 ? C_TOT - 1 : cc;
        wa += sx[cc][col];
    }
    #pragma unroll
    for (int d = -PAD + 1; d <= PAD; d += 2) {
        int cc = c0 + d;
        cc = cc < 0 ? 0 : cc; cc = cc > C_TOT - 1 ? C_TOT - 1 : cc;
        wb += sx[cc][col];
    }
    float winsum = wa + wb;

    // ---- Window pass: T kept in registers only (NO stores here) ----
    float tval[SEG_C];
    #pragma unroll
    for (int j = 0; j < SEG_C; ++j) {
        const int c = c0 + j;
        tval[j] = winsum * inv25;
        int chi = c + 1 + PAD; chi = chi > C_TOT - 1 ? C_TOT - 1 : chi;
        int clo = c - PAD;     clo = clo < 0 ? 0 : clo;
        winsum += sx[chi][col] - sx[clo][col];
    }
    __syncthreads();                    // barrier 2: all window reads of sx done
                                        // (no vmem outstanding -> free drain)

    // ---- Overwrite sx with xd in-place (each (c,col) owned by one thread) ----
    #pragma unroll
    for (int j = 0; j < SEG_C; ++j) {
        const int c = c0 + j;
        sx[c][col] = sx[c][col] - tval[j];
    }
    __syncthreads();                    // barrier 3: xd visible

    // ---- Cross-group phase reduction ----
    if (tid < PERIOD * W) {             // 768 items; waves 12-13 idle (uniform)
        const int p = tid >> 5, cc = tid & (W - 1);
        float s = 0.0f;
        #pragma unroll
        for (int g = 0; g < GROUPS; ++g) s += sx[g * PERIOD + p][cc];
        sv[p][cc] = s * inv14;
    }
    __syncthreads();                    // barrier 4: sv visible

    // ---- Epilogue: ALL global stores, no barrier after -> async retire ----
    const size_t base = (size_t)b * C_TOT * HWSZ + hw0 + col;
    float* __restrict__ Tb = outT + base;
    float* __restrict__ Sb = outS + base;
    float* __restrict__ Rb = outR + base;
    const int pbase = (seg & 1) * SEG_C;   // phase of channel c0+j is pbase + j
    #pragma unroll
    for (int j = 0; j < SEG_C; ++j) {
        const int c = c0 + j;
        const float s  = sv[pbase + j][col];
        const float xd = sx[c][col];
        __builtin_nontemporal_store(tval[j], &Tb[(size_t)c * HWSZ]);
        __builtin_nontemporal_store(s,       &Sb[(size_t)c * HWSZ]);
        __builtin_nontemporal_store(xd - s,  &Rb[(size_t)c * HWSZ]);
    }
}

extern "C" void kernel_launch(void* const* d_in, const int* in_sizes, int n_in,
                              void* d_out, int out_size, void* d_ws, size_t ws_size,
                              hipStream_t stream) {
    const float* x = (const float*)d_in[0];
    // d_in[1] = kernel_size (25), d_in[2] = pe (24): fixed by setup, compiled in.
    float* out = (float*)d_out;
    const size_t N = (size_t)32 * C_TOT * HWSZ;  // 11,010,048 per output tensor

    dim3 grid(HWSZ / W, 32);  // (32 hw tiles, 32 batches) = 1024 blocks
    decomp_kernel<<<grid, NTHREADS, 0, stream>>>(x, out, out + N, out + 2 * N);
}